// Round 19
// baseline (289.874 us; speedup 1.0000x reference)
//
#include <hip/hip_runtime.h>
#include <hip/hip_fp16.h>
#include <stdint.h>

// MultiResolutionHashEncoding — R19: vectorized gather-body I/O
// (contiguous 8 pts/thread: 6 dwordx4 coords + 8 gathers + 2 dwordx4 ws).
//
// R16/R18: 274/277us (noise) = gather ~160 + transpose ~110. Gather dur
//   pinned across 6 structural variants -> residency levers exhausted.
// R19 theory: gather is VMEM-ISSUE-bound: 40 VMEM instr / 8 pts
//   (24 coord dwords + 8 gathers + 8 stores) = 115M instrs = 1.34/cyc/CU.
//   Coords = 60% of issue slots. Contiguous-8-per-thread cuts to 16
//   instrs (6 + 8 + 2). If issue-bound: gather -> 75-100us. If unchanged:
//   ~7 line-req/cyc/XCD is the real service ceiling -> declare roofline.

#define TPB 256

typedef float vfloat4 __attribute__((ext_vector_type(4)));
typedef float vfloat2 __attribute__((ext_vector_type(2)));
typedef uint32_t vuint4 __attribute__((ext_vector_type(4)));

__device__ __forceinline__ uint32_t hash_idx(float cx, float cy, float cz,
                                             int resi, int siz)
{
    const float rf = (float)resi;
    const int x = (int)floorf(cx * rf);
    const int y = (int)floorf(cy * rf);
    const int z = (int)floorf(cz * rf);
    // int32 wraparound multiplies + xor (uint32 = UB-free)
    const uint32_t h = (uint32_t)x * 73856093u
                     ^ (uint32_t)y * 19349663u
                     ^ (uint32_t)z * 83492791u;
    const int32_t hs = (int32_t)h;
    if (siz == (1 << 19)) {
        // numpy abs(INT_MIN)=INT_MIN; python-mod 2^19 == mask
        const uint32_t a = (hs < 0) ? (0u - h) : h;
        return a & 0x7FFFFu;
    } else {
        int32_t a = (hs < 0) ? (int32_t)(0u - h) : hs;
        int32_t r = a % siz;          // compile-time divisor -> magic mul
        if (r < 0) r += siz;
        return (uint32_t)r;
    }
}

__device__ __forceinline__ uint32_t pack_h2(float a, float b)
{
    const __half ha = __float2half_rn(a);
    const __half hb = __float2half_rn(b);
    return (uint32_t)__half_as_ushort(ha)
         | ((uint32_t)__half_as_ushort(hb) << 16);
}

__device__ __forceinline__ vfloat2 unpack_h2(uint32_t v)
{
    vfloat2 r;
    r.x = __half2float(__ushort_as_half((uint16_t)(v & 0xFFFFu)));
    r.y = __half2float(__ushort_as_half((uint16_t)(v >> 16)));
    return r;
}

#define RESI_LIST {16, 22, 30, 42, 58, 80, 111, 153, \
                   212, 294, 406, 561, 776, 1072, 1482, 2048}
#define SIZ_LIST  {4096, 10648, 27000, 74088, 195112, 512000, \
                   524288, 524288, 524288, 524288, 524288, \
                   524288, 524288, 524288, 524288, 524288}

// ---- per-level gather body, vectorized I/O: 8 CONTIGUOUS pts/thread -------
template<int LV>
__device__ __forceinline__ void gather_body(
    const float* __restrict__ coords,
    const float* __restrict__ tables,
    uint32_t* __restrict__ ws,
    int npts, long long pb, int t)
{
    constexpr int RESI[16] = RESI_LIST;
    constexpr int SIZ[16] = SIZ_LIST;

    const long long base = pb * 2048;
    const float* tab = tables + ((size_t)LV << 20);

    // coords for 8 adjacent points: 96B = 6 dwordx4 (was 24 dword loads)
    const vfloat4* cv =
        reinterpret_cast<const vfloat4*>(coords + base * 3) + (size_t)t * 6;
    vfloat4 cf[6];
#pragma unroll
    for (int k = 0; k < 6; ++k) cf[k] = cv[k];
    float flat[24];
#pragma unroll
    for (int k = 0; k < 6; ++k) {
        flat[k * 4 + 0] = cf[k].x; flat[k * 4 + 1] = cf[k].y;
        flat[k * 4 + 2] = cf[k].z; flat[k * 4 + 3] = cf[k].w;
    }

    uint32_t g[8];
#pragma unroll
    for (int j = 0; j < 8; ++j) {
        const uint32_t idx = hash_idx(flat[j * 3 + 0], flat[j * 3 + 1],
                                      flat[j * 3 + 2], RESI[LV], SIZ[LV]);
        const vfloat2 f = *reinterpret_cast<const vfloat2*>(
            tab + ((size_t)idx << 1));
        g[j] = pack_h2(f.x, f.y);
    }

    // 8 packed half2 = 32B = 2 dwordx4 NT stores (was 8 dword stores)
    vuint4* wl = reinterpret_cast<vuint4*>(
        ws + (size_t)(LV - 5) * npts + base) + (size_t)t * 2;
    vuint4 s0 = {g[0], g[1], g[2], g[3]};
    vuint4 s1 = {g[4], g[5], g[6], g[7]};
    __builtin_nontemporal_store(s0, wl + 0);
    __builtin_nontemporal_store(s1, wl + 1);
}

// ---- single balanced gather launch (R14 schedule, unchanged) --------------
__global__ __launch_bounds__(TPB) void hashenc_gather_merged(
    const float* __restrict__ coords,
    const float* __restrict__ tables,
    uint32_t* __restrict__ ws,
    int npts)
{
    const int t = threadIdx.x;
    const int c = blockIdx.x & 7;
    const long long k = blockIdx.x >> 3;
    const long long npb = (long long)npts >> 11;   // npts/2048

    if (k < npb) {
        switch (c) {   // wave-uniform, compile-time bodies
            case 0: gather_body<5>(coords, tables, ws, npts, k, t); break;
            case 1: gather_body<6>(coords, tables, ws, npts, k, t); break;
            case 2: gather_body<7>(coords, tables, ws, npts, k, t); break;
            case 3: gather_body<8>(coords, tables, ws, npts, k, t); break;
            case 4: gather_body<9>(coords, tables, ws, npts, k, t); break;
            case 5: gather_body<10>(coords, tables, ws, npts, k, t); break;
            case 6: gather_body<11>(coords, tables, ws, npts, k, t); break;
            case 7: gather_body<12>(coords, tables, ws, npts, k, t); break;
        }
    } else {
        const long long per_class = (3 * npb + 7) >> 3;
        const long long ti = (long long)c * per_class + (k - npb);
        if (ti < 3 * npb) {
            const long long pb = ti % npb;
            switch ((int)(ti / npb)) {
                case 0: gather_body<13>(coords, tables, ws, npts, pb, t); break;
                case 1: gather_body<14>(coords, tables, ws, npts, pb, t); break;
                case 2: gather_body<15>(coords, tables, ws, npts, pb, t); break;
            }
        }
    }
}

// ---- Phase 2: coarse gather (levels 0-4) + transpose (unchanged) ----------
__global__ __launch_bounds__(TPB) void hashenc_transpose_fused(
    const float* __restrict__ coords,
    const float* __restrict__ tables,
    const uint32_t* __restrict__ ws,
    float* __restrict__ out,
    int npts)
{
    constexpr int RESI[16] = RESI_LIST;
    constexpr int SIZ[16] = SIZ_LIST;

    __shared__ float buf[128 * 33];

    const int t = threadIdx.x;
    const long long pbase = (long long)blockIdx.x * TPB;
    const long long p = pbase + t;

    const float cx = coords[3 * p + 0];
    const float cy = coords[3 * p + 1];
    const float cz = coords[3 * p + 2];

    vfloat2 feat[16];
#pragma unroll
    for (int l = 0; l < 5; ++l) {   // inline coarse gathers (hot tables, f32)
        const uint32_t idx = hash_idx(cx, cy, cz, RESI[l], SIZ[l]);
        feat[l] = *reinterpret_cast<const vfloat2*>(
            tables + ((size_t)l << 20) + ((size_t)idx << 1));
    }
#pragma unroll
    for (int l = 5; l < 16; ++l) {  // fine levels from packed ws
        const uint32_t v = ws[(size_t)(l - 5) * npts + p];
        feat[l] = unpack_h2(v);
    }

    float* oblk = out + pbase * 32;
#pragma unroll
    for (int h = 0; h < 2; ++h) {
        if ((t >> 7) == h) {
            const int r = t & 127;
#pragma unroll
            for (int l = 0; l < 16; ++l) {
                buf[r * 33 + 2 * l + 0] = feat[l].x;
                buf[r * 33 + 2 * l + 1] = feat[l].y;
            }
        }
        __syncthreads();
#pragma unroll
        for (int k = 0; k < 4; ++k) {
            const int f = k * 1024 + t * 4;
            const int row = f >> 5;
            const int col = f & 31;
            const vfloat4 v = *reinterpret_cast<const vfloat4*>(&buf[row * 33 + col]);
            __builtin_nontemporal_store(v,
                reinterpret_cast<vfloat4*>(&oblk[(long long)h * 4096 + f]));
        }
        __syncthreads();
    }
}

// ---- Fallback: R6 single-phase (ws too small / odd N) ---------------------
__global__ __launch_bounds__(TPB) void hashenc_kernel(
    const float* __restrict__ coords,
    const float* __restrict__ tables,
    float* __restrict__ out,
    int npts)
{
    constexpr int RESI[16] = RESI_LIST;
    constexpr int SIZ[16] = SIZ_LIST;

    __shared__ float buf[128 * 33];

    const int t = threadIdx.x;
    const long long pbase = (long long)blockIdx.x * TPB;
    const long long p = pbase + t;

    const float cx = coords[3 * p + 0];
    const float cy = coords[3 * p + 1];
    const float cz = coords[3 * p + 2];

    float2 feat[16];
#pragma unroll
    for (int l = 0; l < 16; ++l) {
        const uint32_t idx = hash_idx(cx, cy, cz, RESI[l], SIZ[l]);
        feat[l] = *reinterpret_cast<const float2*>(
            tables + ((size_t)l << 20) + ((size_t)idx << 1));
    }

    float* oblk = out + pbase * 32;
#pragma unroll
    for (int h = 0; h < 2; ++h) {
        if ((t >> 7) == h) {
            const int r = t & 127;
#pragma unroll
            for (int l = 0; l < 16; ++l) {
                buf[r * 33 + 2 * l + 0] = feat[l].x;
                buf[r * 33 + 2 * l + 1] = feat[l].y;
            }
        }
        __syncthreads();
#pragma unroll
        for (int k = 0; k < 4; ++k) {
            const int f = k * 1024 + t * 4;
            const int row = f >> 5;
            const int col = f & 31;
            const vfloat4 v = *reinterpret_cast<const vfloat4*>(&buf[row * 33 + col]);
            __builtin_nontemporal_store(v,
                reinterpret_cast<vfloat4*>(&oblk[(long long)h * 4096 + f]));
        }
        __syncthreads();
    }
}

extern "C" void kernel_launch(void* const* d_in, const int* in_sizes, int n_in,
                              void* d_out, int out_size, void* d_ws, size_t ws_size,
                              hipStream_t stream)
{
    const float* coords = (const float*)d_in[0];
    const float* tables = (const float*)d_in[1];
    float* out = (float*)d_out;
    const int npts = in_sizes[0] / 3;   // 2^21

    const size_t need = (size_t)11 * (size_t)npts * sizeof(uint32_t);
    if (ws_size >= need && (npts % 2048) == 0) {
        uint32_t* ws = (uint32_t*)d_ws;
        const long long npb = npts / 2048;
        const long long per_class = (3 * npb + 7) / 8;
        const dim3 g((unsigned)(8 * (npb + per_class))), b(TPB);
        hipLaunchKernelGGL(hashenc_gather_merged, g, b, 0, stream,
                           coords, tables, ws, npts);
        hipLaunchKernelGGL(hashenc_transpose_fused, dim3(npts / TPB), b, 0, stream,
                           coords, tables, (const uint32_t*)d_ws, out, npts);
    } else {
        hipLaunchKernelGGL(hashenc_kernel, dim3(npts / TPB), dim3(TPB), 0, stream,
                           coords, tables, out, npts);
    }
}

// Round 20
// 277.244 us; speedup vs baseline: 1.0456x; 1.0456x over previous
//
#include <hip/hip_runtime.h>
#include <hip/hip_fp16.h>
#include <stdint.h>

// MultiResolutionHashEncoding — R20: revert to R18 (best, 274us).
//
// FINAL STRUCTURE. Two phases:
//   1) hashenc_gather_merged: fine levels 5-15, one-level-per-XCD-class
//      (bid%8 round-robin), balanced tail; packed-half2 NT ws stores.
//   2) hashenc_transpose_fused: coarse levels 0-4 inline (2.47MB tables,
//      L2-hot) + ws read + LDS transpose + NT vec4 out stores.
//
// Ceiling evidence (R4-R19):
//   gather ~160us pinned across: occupancy 42->84% (R6), MLP 4->8 (R10),
//   launches 12->6->2->1 (R9-R14), NT loads (R15, worse), VMEM instr
//   40->16/8pts (R19, worse) => L2 random line-request service bound:
//   23M requests @ ~7 req/cyc/XCD. Not bytes, not issue, not latency-
//   hiding — request service.
//   transpose ~110us: 385MB @ ~3.5TB/s + 10M coarse gather requests.
//   R17 overlap attempt: +29us (launch ramps + L2 contention).
// fp16 ws pack: absmax 2.44e-4, 4x under 1e-3 threshold (values U(+-0.05)).

#define TPB 256

typedef float vfloat4 __attribute__((ext_vector_type(4)));
typedef float vfloat2 __attribute__((ext_vector_type(2)));

__device__ __forceinline__ uint32_t hash_idx(float cx, float cy, float cz,
                                             int resi, int siz)
{
    const float rf = (float)resi;
    const int x = (int)floorf(cx * rf);
    const int y = (int)floorf(cy * rf);
    const int z = (int)floorf(cz * rf);
    // int32 wraparound multiplies + xor (uint32 = UB-free)
    const uint32_t h = (uint32_t)x * 73856093u
                     ^ (uint32_t)y * 19349663u
                     ^ (uint32_t)z * 83492791u;
    const int32_t hs = (int32_t)h;
    if (siz == (1 << 19)) {
        // numpy abs(INT_MIN)=INT_MIN; python-mod 2^19 == mask
        const uint32_t a = (hs < 0) ? (0u - h) : h;
        return a & 0x7FFFFu;
    } else {
        int32_t a = (hs < 0) ? (int32_t)(0u - h) : hs;
        int32_t r = a % siz;          // compile-time divisor -> magic mul
        if (r < 0) r += siz;
        return (uint32_t)r;
    }
}

__device__ __forceinline__ uint32_t pack_h2(float a, float b)
{
    const __half ha = __float2half_rn(a);
    const __half hb = __float2half_rn(b);
    return (uint32_t)__half_as_ushort(ha)
         | ((uint32_t)__half_as_ushort(hb) << 16);
}

__device__ __forceinline__ vfloat2 unpack_h2(uint32_t v)
{
    vfloat2 r;
    r.x = __half2float(__ushort_as_half((uint16_t)(v & 0xFFFFu)));
    r.y = __half2float(__ushort_as_half((uint16_t)(v >> 16)));
    return r;
}

#define RESI_LIST {16, 22, 30, 42, 58, 80, 111, 153, \
                   212, 294, 406, 561, 776, 1072, 1482, 2048}
#define SIZ_LIST  {4096, 10648, 27000, 74088, 195112, 512000, \
                   524288, 524288, 524288, 524288, 524288, \
                   524288, 524288, 524288, 524288, 524288}

// ---- compile-time per-level gather body: point-block pb (2048 pts) --------
template<int LV>
__device__ __forceinline__ void gather_body(
    const float* __restrict__ coords,
    const float* __restrict__ tables,
    uint32_t* __restrict__ ws,
    int npts, long long pb, int t)
{
    constexpr int RESI[16] = RESI_LIST;
    constexpr int SIZ[16] = SIZ_LIST;

    const long long base = pb * 2048;
    const float* tab = tables + ((size_t)LV << 20);

    uint32_t g[8];
#pragma unroll
    for (int j = 0; j < 8; ++j) {
        const long long p = base + j * 256 + t;
        const float cx = coords[3 * p + 0];   // regular loads (R15 lesson)
        const float cy = coords[3 * p + 1];
        const float cz = coords[3 * p + 2];
        const uint32_t idx = hash_idx(cx, cy, cz, RESI[LV], SIZ[LV]);
        const vfloat2 f = *reinterpret_cast<const vfloat2*>(
            tab + ((size_t)idx << 1));
        g[j] = pack_h2(f.x, f.y);
    }
    uint32_t* wl = ws + (size_t)(LV - 5) * npts + base;
#pragma unroll
    for (int j = 0; j < 8; ++j)   // NT: don't evict the L2-hot table
        __builtin_nontemporal_store(g[j], wl + j * 256 + t);
}

// ---- single balanced gather launch ----------------------------------------
// class c = bid%8 (XCD): k<npb -> primary level 5+c, pb=k;
// else tail unit ti = c*per_class + (k-npb) in [0,3*npb):
//   level = 13 + ti/npb, pb = ti%npb. Sequential per XCD.
__global__ __launch_bounds__(TPB) void hashenc_gather_merged(
    const float* __restrict__ coords,
    const float* __restrict__ tables,
    uint32_t* __restrict__ ws,
    int npts)
{
    const int t = threadIdx.x;
    const int c = blockIdx.x & 7;
    const long long k = blockIdx.x >> 3;
    const long long npb = (long long)npts >> 11;   // npts/2048

    if (k < npb) {
        switch (c) {   // wave-uniform, compile-time bodies
            case 0: gather_body<5>(coords, tables, ws, npts, k, t); break;
            case 1: gather_body<6>(coords, tables, ws, npts, k, t); break;
            case 2: gather_body<7>(coords, tables, ws, npts, k, t); break;
            case 3: gather_body<8>(coords, tables, ws, npts, k, t); break;
            case 4: gather_body<9>(coords, tables, ws, npts, k, t); break;
            case 5: gather_body<10>(coords, tables, ws, npts, k, t); break;
            case 6: gather_body<11>(coords, tables, ws, npts, k, t); break;
            case 7: gather_body<12>(coords, tables, ws, npts, k, t); break;
        }
    } else {
        const long long per_class = (3 * npb + 7) >> 3;
        const long long ti = (long long)c * per_class + (k - npb);
        if (ti < 3 * npb) {
            const long long pb = ti % npb;
            switch ((int)(ti / npb)) {
                case 0: gather_body<13>(coords, tables, ws, npts, pb, t); break;
                case 1: gather_body<14>(coords, tables, ws, npts, pb, t); break;
                case 2: gather_body<15>(coords, tables, ws, npts, pb, t); break;
            }
        }
    }
}

// ---- Phase 2: coarse gather (levels 0-4, tables 2.47MB = L2-hot)
//      + transpose packed ws fine levels -> out (N,32) ---------------------
__global__ __launch_bounds__(TPB) void hashenc_transpose_fused(
    const float* __restrict__ coords,
    const float* __restrict__ tables,
    const uint32_t* __restrict__ ws,
    float* __restrict__ out,
    int npts)
{
    constexpr int RESI[16] = RESI_LIST;
    constexpr int SIZ[16] = SIZ_LIST;

    __shared__ float buf[128 * 33];

    const int t = threadIdx.x;
    const long long pbase = (long long)blockIdx.x * TPB;
    const long long p = pbase + t;

    const float cx = coords[3 * p + 0];
    const float cy = coords[3 * p + 1];
    const float cz = coords[3 * p + 2];

    vfloat2 feat[16];
#pragma unroll
    for (int l = 0; l < 5; ++l) {   // inline coarse gathers (hot tables, f32)
        const uint32_t idx = hash_idx(cx, cy, cz, RESI[l], SIZ[l]);
        feat[l] = *reinterpret_cast<const vfloat2*>(
            tables + ((size_t)l << 20) + ((size_t)idx << 1));
    }
#pragma unroll
    for (int l = 5; l < 16; ++l) {  // fine levels from packed ws (cached)
        const uint32_t v = ws[(size_t)(l - 5) * npts + p];
        feat[l] = unpack_h2(v);
    }

    float* oblk = out + pbase * 32;
#pragma unroll
    for (int h = 0; h < 2; ++h) {
        if ((t >> 7) == h) {
            const int r = t & 127;
#pragma unroll
            for (int l = 0; l < 16; ++l) {
                buf[r * 33 + 2 * l + 0] = feat[l].x;
                buf[r * 33 + 2 * l + 1] = feat[l].y;
            }
        }
        __syncthreads();
#pragma unroll
        for (int k = 0; k < 4; ++k) {
            const int f = k * 1024 + t * 4;
            const int row = f >> 5;
            const int col = f & 31;
            const vfloat4 v = *reinterpret_cast<const vfloat4*>(&buf[row * 33 + col]);
            __builtin_nontemporal_store(v,
                reinterpret_cast<vfloat4*>(&oblk[(long long)h * 4096 + f]));
        }
        __syncthreads();
    }
}

// ---- Fallback: R6 single-phase (ws too small / odd N) ---------------------
__global__ __launch_bounds__(TPB) void hashenc_kernel(
    const float* __restrict__ coords,
    const float* __restrict__ tables,
    float* __restrict__ out,
    int npts)
{
    constexpr int RESI[16] = RESI_LIST;
    constexpr int SIZ[16] = SIZ_LIST;

    __shared__ float buf[128 * 33];

    const int t = threadIdx.x;
    const long long pbase = (long long)blockIdx.x * TPB;
    const long long p = pbase + t;

    const float cx = coords[3 * p + 0];
    const float cy = coords[3 * p + 1];
    const float cz = coords[3 * p + 2];

    float2 feat[16];
#pragma unroll
    for (int l = 0; l < 16; ++l) {
        const uint32_t idx = hash_idx(cx, cy, cz, RESI[l], SIZ[l]);
        feat[l] = *reinterpret_cast<const float2*>(
            tables + ((size_t)l << 20) + ((size_t)idx << 1));
    }

    float* oblk = out + pbase * 32;
#pragma unroll
    for (int h = 0; h < 2; ++h) {
        if ((t >> 7) == h) {
            const int r = t & 127;
#pragma unroll
            for (int l = 0; l < 16; ++l) {
                buf[r * 33 + 2 * l + 0] = feat[l].x;
                buf[r * 33 + 2 * l + 1] = feat[l].y;
            }
        }
        __syncthreads();
#pragma unroll
        for (int k = 0; k < 4; ++k) {
            const int f = k * 1024 + t * 4;
            const int row = f >> 5;
            const int col = f & 31;
            const vfloat4 v = *reinterpret_cast<const vfloat4*>(&buf[row * 33 + col]);
            __builtin_nontemporal_store(v,
                reinterpret_cast<vfloat4*>(&oblk[(long long)h * 4096 + f]));
        }
        __syncthreads();
    }
}

extern "C" void kernel_launch(void* const* d_in, const int* in_sizes, int n_in,
                              void* d_out, int out_size, void* d_ws, size_t ws_size,
                              hipStream_t stream)
{
    const float* coords = (const float*)d_in[0];
    const float* tables = (const float*)d_in[1];
    float* out = (float*)d_out;
    const int npts = in_sizes[0] / 3;   // 2^21

    const size_t need = (size_t)11 * (size_t)npts * sizeof(uint32_t);
    if (ws_size >= need && (npts % 2048) == 0) {
        uint32_t* ws = (uint32_t*)d_ws;
        const long long npb = npts / 2048;
        const long long per_class = (3 * npb + 7) / 8;
        const dim3 g((unsigned)(8 * (npb + per_class))), b(TPB);
        hipLaunchKernelGGL(hashenc_gather_merged, g, b, 0, stream,
                           coords, tables, ws, npts);
        hipLaunchKernelGGL(hashenc_transpose_fused, dim3(npts / TPB), b, 0, stream,
                           coords, tables, (const uint32_t*)d_ws, out, npts);
    } else {
        hipLaunchKernelGGL(hashenc_kernel, dim3(npts / TPB), dim3(TPB), 0, stream,
                           coords, tables, out, npts);
    }
}